// Round 1
// baseline (211.859 us; speedup 1.0000x reference)
//
#include <hip/hip_runtime.h>

// Problem constants (fixed by the reference setup)
#define AN 100000   // anchors
#define BN 8        // batch
#define MN 64       // gt boxes per sample
#define CN 80       // classes

// ---------------------------------------------------------------------------
// ws layout:
//   [0,8)        double cls_total
//   [16,48)      float num_pos[8]
//   [48,80)      float reg_sum[8]
//   [80,112)     float wcls[8]
//   [128, ...)   float status[BN*AN]   (3.2 MB)
// ---------------------------------------------------------------------------

__global__ __launch_bounds__(256) void iou_status_kernel(
    const float* __restrict__ anchors,    // [AN,4]
    const float* __restrict__ regs,       // [BN,AN,4]
    const float* __restrict__ anns,       // [BN,MN,5]
    float* __restrict__ status,           // [BN*AN]
    float* __restrict__ num_pos,          // [BN]
    float* __restrict__ reg_sum)          // [BN]
{
    __shared__ float bx1[MN], by1[MN], bx2[MN], by2[MN], barea[MN];
    const int tid = threadIdx.x;
    const int b   = blockIdx.y;
    if (tid < MN) {
        const float* p = anns + ((size_t)b * MN + tid) * 5;
        float x1 = p[0], y1 = p[1], x2 = p[2], y2 = p[3];
        bx1[tid] = x1; by1[tid] = y1; bx2[tid] = x2; by2[tid] = y2;
        barea[tid] = (x2 - x1) * (y2 - y1);
    }
    __syncthreads();

    const int a = blockIdx.x * 256 + tid;
    float posf = 0.f, rsum = 0.f;
    if (a < AN) {
        const float4 an = *(const float4*)(anchors + (size_t)a * 4);
        const float ax1 = an.x, ay1 = an.y, ax2 = an.z, ay2 = an.w;
        const float aw = ax2 - ax1, ah = ay2 - ay1;
        const float aarea = aw * ah;

        float best = -1.f;
        int   barg = 0;
        #pragma unroll 8
        for (int m = 0; m < MN; ++m) {
            float iw = fminf(ax2, bx2[m]) - fmaxf(ax1, bx1[m]);
            iw = fmaxf(iw, 0.f);
            float ih = fminf(ay2, by2[m]) - fmaxf(ay1, by1[m]);
            ih = fmaxf(ih, 0.f);
            float inter = iw * ih;
            float ua = fmaxf(aarea + barea[m] - inter, 1e-8f);
            float iou = inter / ua;          // IEEE div: match ref thresholds
            if (iou > best) { best = iou; barg = m; }  // strict >: first-max, like argmax
        }

        float st = (best >= 0.5f) ? 1.f : ((best < 0.4f) ? 0.f : -1.f);
        status[(size_t)b * AN + a] = st;

        if (st > 0.5f) {
            posf = 1.f;
            float gx1 = bx1[barg], gy1 = by1[barg], gx2 = bx2[barg], gy2 = by2[barg];
            float gw = gx2 - gx1, gh = gy2 - gy1;
            float gcx = gx1 + 0.5f * gw, gcy = gy1 + 0.5f * gh;
            gw = fmaxf(gw, 1.f); gh = fmaxf(gh, 1.f);
            float acx = ax1 + 0.5f * aw, acy = ay1 + 0.5f * ah;
            float t0 = (gcx - acx) / aw * 10.f;          // / std 0.1
            float t1 = (gcy - acy) / ah * 10.f;
            float t2 = __logf(gw / aw) * 5.f;            // / std 0.2
            float t3 = __logf(gh / ah) * 5.f;
            const float4 rg = *(const float4*)(regs + ((size_t)b * AN + a) * 4);
            float d0 = fabsf(t0 - rg.x), d1 = fabsf(t1 - rg.y);
            float d2 = fabsf(t2 - rg.z), d3 = fabsf(t3 - rg.w);
            const float TH = 1.f / 9.f, HB = 0.5f / 9.f;
            rsum  = (d0 <= TH ? 4.5f * d0 * d0 : d0 - HB);
            rsum += (d1 <= TH ? 4.5f * d1 * d1 : d1 - HB);
            rsum += (d2 <= TH ? 4.5f * d2 * d2 : d2 - HB);
            rsum += (d3 <= TH ? 4.5f * d3 * d3 : d3 - HB);
        }
    }

    // block reduction (one atomic pair per block)
    __shared__ float s0[256], s1[256];
    s0[tid] = posf; s1[tid] = rsum;
    __syncthreads();
    #pragma unroll
    for (int off = 128; off > 0; off >>= 1) {
        if (tid < off) { s0[tid] += s0[tid + off]; s1[tid] += s1[tid + off]; }
        __syncthreads();
    }
    if (tid == 0) {
        atomicAdd(&num_pos[b], s0[0]);
        atomicAdd(&reg_sum[b], s1[0]);
    }
}

__global__ void finalize_weights(const float* __restrict__ num_pos,
                                 const float* __restrict__ reg_sum,
                                 float* __restrict__ wcls,
                                 float* __restrict__ out)
{
    if (threadIdx.x == 0 && blockIdx.x == 0) {
        float racc = 0.f;
        for (int b = 0; b < BN; ++b) {
            float np = num_pos[b];
            wcls[b] = 1.f / ((float)BN * fmaxf(np, 1.f));
            if (np > 0.f) racc += reg_sum[b] / (4.f * np);  // max(4*np,1)==4*np since np>=1
        }
        out[1] = racc / (float)BN;
    }
}

__global__ __launch_bounds__(256) void focal_kernel(
    const float* __restrict__ cls,      // [BN*AN*CN]
    const float* __restrict__ status,   // [BN*AN]
    const float* __restrict__ wcls,     // [BN]
    double* __restrict__ cls_total)
{
    const int NV = BN * AN * CN / 4;    // 16,000,000 float4s
    float acc = 0.f;
    for (int v = blockIdx.x * blockDim.x + threadIdx.x; v < NV;
         v += gridDim.x * blockDim.x) {
        const int ag = v / 20;          // anchor global index (CN/4 = 20 float4 per anchor)
        const float s = status[ag];
        if (s < -0.5f) continue;        // ignore band: skip loads entirely
        const int b = ag / AN;
        const float w = wcls[b];
        const float4 p4 = *(const float4*)(cls + (size_t)v * 4);

        float p, t;
        p = fminf(fmaxf(p4.x, 1e-4f), 1.f - 1e-4f);
        float term0 = 0.75f * p * p * (-__logf(1.f - p));
        if (s > 0.5f && (v % 20) == 0)  // class 0 of a positive anchor
            term0 = 0.25f * (1.f - p) * (1.f - p) * (-__logf(p));
        t = term0;
        p = fminf(fmaxf(p4.y, 1e-4f), 1.f - 1e-4f);
        t += 0.75f * p * p * (-__logf(1.f - p));
        p = fminf(fmaxf(p4.z, 1e-4f), 1.f - 1e-4f);
        t += 0.75f * p * p * (-__logf(1.f - p));
        p = fminf(fmaxf(p4.w, 1e-4f), 1.f - 1e-4f);
        t += 0.75f * p * p * (-__logf(1.f - p));

        acc += t * w;
    }

    __shared__ float sh[256];
    sh[threadIdx.x] = acc;
    __syncthreads();
    #pragma unroll
    for (int off = 128; off > 0; off >>= 1) {
        if (threadIdx.x < off) sh[threadIdx.x] += sh[threadIdx.x + off];
        __syncthreads();
    }
    if (threadIdx.x == 0) atomicAdd(cls_total, (double)sh[0]);
}

__global__ void write_cls(const double* __restrict__ cls_total,
                          float* __restrict__ out)
{
    if (threadIdx.x == 0 && blockIdx.x == 0)
        out[0] = (float)(*cls_total);
}

extern "C" void kernel_launch(void* const* d_in, const int* in_sizes, int n_in,
                              void* d_out, int out_size, void* d_ws, size_t ws_size,
                              hipStream_t stream) {
    const float* cls     = (const float*)d_in[0];   // [8,100000,80]
    const float* regs    = (const float*)d_in[1];   // [8,100000,4]
    const float* anchors = (const float*)d_in[2];   // [1,100000,4]
    const float* anns    = (const float*)d_in[3];   // [8,64,5]
    float* out = (float*)d_out;

    char* ws = (char*)d_ws;
    double* cls_total = (double*)(ws + 0);
    float*  num_pos   = (float*)(ws + 16);
    float*  reg_sum   = (float*)(ws + 48);
    float*  wcls      = (float*)(ws + 80);
    float*  status    = (float*)(ws + 128);

    // zero accumulators (capture-safe)
    hipMemsetAsync(d_ws, 0, 128, stream);

    dim3 gridA((AN + 255) / 256, BN);
    iou_status_kernel<<<gridA, 256, 0, stream>>>(anchors, regs, anns,
                                                 status, num_pos, reg_sum);

    finalize_weights<<<1, 64, 0, stream>>>(num_pos, reg_sum, wcls, out);

    focal_kernel<<<2048, 256, 0, stream>>>(cls, status, wcls, cls_total);

    write_cls<<<1, 64, 0, stream>>>(cls_total, out);
}